// Round 1
// baseline (392.615 us; speedup 1.0000x reference)
//
#include <hip/hip_runtime.h>

// Problem constants: B=4, C=19, H=512, W=1024
#define NPIX 2097152              // B*H*W
#define NT2  1048576              // NPIX/2 (float2 threads in k_loss)
#define NT4  524288               // loss array in uint4 units
#define NCH  19
#define CPL2 262144               // float2 per channel plane (512*1024/2), = 2^18
#define KSEL 1468006u             // int(0.7 * NPIX)
#define LBLK 4096                 // NT2/256
#define HB   512                  // histogram blocks
#define H1B  4096                 // level-1 bins (bits 31..20)
#define H2B  1024                 // level-2/3 bins (10 bits)

// workspace layout (bytes), total ~8.5 MB
#define OFF_COMB1 (NPIX*4)                 //  8388608: 4096 u32
#define OFF_COMB2 (OFF_COMB1 + H1B*4)      //  8404992: 1024 u32 (reused lvl3)
#define OFF_PART  (OFF_COMB2 + H2B*4)      //  8409088: 512 doubles
#define OFF_CTRL  (OFF_PART + HB*8)        //  8413184

struct Ctrl { unsigned p1, n1, p2, n2; };

// ---------------------------------------------------------------------------
// K1: per-pixel loss, float2/thread to stay under the 64-VGPR occupancy cliff
// (84 VGPR -> 4 waves/SIMD; target <=64 -> 8 waves/SIMD). Block 0 also zeroes
// comb1+comb2 (5120 u32) so no memset node is needed.
// ---------------------------------------------------------------------------
__global__ __launch_bounds__(256, 8) void k_loss(
    const float* __restrict__ logits, const float* __restrict__ smooth,
    const float* __restrict__ wgt, float* __restrict__ loss,
    unsigned* __restrict__ combz)
{
    if (blockIdx.x == 0) {
        for (int j = threadIdx.x; j < H1B + H2B; j += 256) combz[j] = 0u;
    }
    int tid = blockIdx.x * 256 + threadIdx.x;     // 0..NT2-1
    int img = tid >> 18;                          // CPL2 = 2^18 float2 per plane
    int rem = tid & (CPL2 - 1);
    const float2* L = (const float2*)logits + (size_t)img * (NCH * CPL2) + rem;
    const float2* S = (const float2*)smooth + (size_t)img * (NCH * CPL2) + rem;

    // depth-4 prefetch ring: 8 independent 8B loads in flight per wave
    float2 xb[4], sb[4];
    #pragma unroll
    for (int i = 0; i < 4; ++i) {
        xb[i] = L[(size_t)i * CPL2];
        sb[i] = S[(size_t)i * CPL2];
    }

    float m0 = -3.4e38f, m1 = -3.4e38f;
    float s0 = 0.f, s1 = 0.f;
    float sw0 = 0.f, sw1 = 0.f;
    float swl0 = 0.f, swl1 = 0.f;

    #pragma unroll
    for (int c = 0; c < NCH; ++c) {
        float2 xv = xb[c & 3];
        float2 sv = sb[c & 3];
        if (c + 4 < NCH) {                        // issue next loads early
            xb[c & 3] = L[(size_t)(c + 4) * CPL2];
            sb[c & 3] = S[(size_t)(c + 4) * CPL2];
        }
        float wc = wgt[c];

        float n0 = fmaxf(m0, xv.x), n1 = fmaxf(m1, xv.y);
        s0 = s0 * __expf(m0 - n0) + __expf(xv.x - n0);
        s1 = s1 * __expf(m1 - n1) + __expf(xv.y - n1);
        m0 = n0; m1 = n1;

        float t0 = sv.x * wc, t1 = sv.y * wc;
        sw0 += t0; sw1 += t1;
        swl0 += t0 * xv.x; swl1 += t1 * xv.y;
    }

    float l0 = fmaxf((m0 + __logf(s0)) * sw0 - swl0, 0.f);
    float l1 = fmaxf((m1 + __logf(s1)) * sw1 - swl1, 0.f);
    ((float2*)loss)[tid] = make_float2(l0, l1);
}

// ---------------------------------------------------------------------------
// H1: 512-block LDS histogram of top-12 bits; flush nonzero bins via global
// atomics into comb1 (max chain depth 512 per address — ~us-scale).
// ---------------------------------------------------------------------------
__global__ __launch_bounds__(256) void k_hist1(
    const uint4* __restrict__ lb, unsigned* __restrict__ comb1)
{
    __shared__ unsigned h[H1B];
    int t = threadIdx.x;
    #pragma unroll
    for (int j = t; j < H1B; j += 256) h[j] = 0;
    __syncthreads();
    int base = blockIdx.x * (NT4 / HB);           // 1024 uint4 per block
    #pragma unroll
    for (int i = 0; i < NT4 / HB / 256; ++i) {
        uint4 v = lb[base + i * 256 + t];
        atomicAdd(&h[v.x >> 20], 1u);
        atomicAdd(&h[v.y >> 20], 1u);
        atomicAdd(&h[v.z >> 20], 1u);
        atomicAdd(&h[v.w >> 20], 1u);
    }
    __syncthreads();
    for (int j = t; j < H1B; j += 256)
        if (h[j]) atomicAdd(&comb1[j], h[j]);
}

// ---------------------------------------------------------------------------
// S1: single-block suffix-scan over 4096 bins -> p1 (12-bit prefix), n1
// ---------------------------------------------------------------------------
__global__ __launch_bounds__(256) void k_sel1(
    const unsigned* __restrict__ comb, Ctrl* __restrict__ ctrl)
{
    __shared__ unsigned bins[H1B];
    __shared__ unsigned cs[256];
    __shared__ unsigned sh_t0, sh_base;
    int t = threadIdx.x;
    for (int j = t; j < H1B; j += 256) bins[j] = comb[j];
    __syncthreads();
    unsigned sum = 0;
    #pragma unroll
    for (int j = 0; j < 16; ++j) sum += bins[t * 16 + j];
    cs[t] = sum; __syncthreads();
    for (int off = 1; off < 256; off <<= 1) {     // inclusive suffix scan
        unsigned v = (t + off < 256) ? cs[t + off] : 0u;
        __syncthreads();
        cs[t] += v;
        __syncthreads();
    }
    unsigned St = cs[t], Sn = (t < 255) ? cs[t + 1] : 0u;
    if (St >= KSEL && Sn < KSEL) { sh_t0 = (unsigned)t; sh_base = Sn; }
    __syncthreads();
    if (t == 0) {
        unsigned cum = sh_base;
        for (int b = (int)sh_t0 * 16 + 15;; --b) {
            unsigned c = bins[b];
            if (cum + c >= KSEL) { ctrl->p1 = (unsigned)b; ctrl->n1 = KSEL - cum; break; }
            cum += c;
        }
    }
}

// ---------------------------------------------------------------------------
// H2: candidates with top12==p1, histogram bits 19..10 -> atomic comb2
// ---------------------------------------------------------------------------
__global__ __launch_bounds__(256) void k_hist2(
    const uint4* __restrict__ lb, const Ctrl* __restrict__ ctrl,
    unsigned* __restrict__ comb2)
{
    __shared__ unsigned h[H2B];
    unsigned p1 = ctrl->p1;
    int t = threadIdx.x;
    #pragma unroll
    for (int j = t; j < H2B; j += 256) h[j] = 0;
    __syncthreads();
    int base = blockIdx.x * (NT4 / HB);
    #pragma unroll
    for (int i = 0; i < NT4 / HB / 256; ++i) {
        uint4 v = lb[base + i * 256 + t];
        if ((v.x >> 20) == p1) atomicAdd(&h[(v.x >> 10) & 1023u], 1u);
        if ((v.y >> 20) == p1) atomicAdd(&h[(v.y >> 10) & 1023u], 1u);
        if ((v.z >> 20) == p1) atomicAdd(&h[(v.z >> 10) & 1023u], 1u);
        if ((v.w >> 20) == p1) atomicAdd(&h[(v.w >> 10) & 1023u], 1u);
    }
    __syncthreads();
    for (int j = t; j < H2B; j += 256)
        if (h[j]) atomicAdd(&comb2[j], h[j]);
}

// ---------------------------------------------------------------------------
// S2: suffix-scan comb2 -> p2 (22-bit prefix), n2; re-zeroes comb2 for H3
// ---------------------------------------------------------------------------
__global__ __launch_bounds__(256) void k_sel2(
    unsigned* __restrict__ comb2, Ctrl* __restrict__ ctrl)
{
    __shared__ unsigned bins[H2B];
    __shared__ unsigned cs[256];
    __shared__ unsigned sh_t0, sh_base;
    int t = threadIdx.x;
    unsigned need = ctrl->n1, pref = ctrl->p1;
    for (int j = t; j < H2B; j += 256) { bins[j] = comb2[j]; comb2[j] = 0u; }
    __syncthreads();
    unsigned sum = bins[t*4] + bins[t*4+1] + bins[t*4+2] + bins[t*4+3];
    cs[t] = sum; __syncthreads();
    for (int off = 1; off < 256; off <<= 1) {
        unsigned v = (t + off < 256) ? cs[t + off] : 0u;
        __syncthreads();
        cs[t] += v;
        __syncthreads();
    }
    unsigned St = cs[t], Sn = (t < 255) ? cs[t + 1] : 0u;
    if (St >= need && Sn < need) { sh_t0 = (unsigned)t; sh_base = Sn; }
    __syncthreads();
    if (t == 0) {
        unsigned cum = sh_base;
        for (int b = (int)sh_t0 * 4 + 3;; --b) {
            unsigned c = bins[b];
            if (cum + c >= need) {
                ctrl->p2 = (pref << 10) | (unsigned)b;
                ctrl->n2 = need - cum;
                break;
            }
            cum += c;
        }
    }
}

// ---------------------------------------------------------------------------
// H3+SUM: candidates with top22==p2 histogrammed on bits 9..0 (bin == exact
// float value!); values strictly above the p2 range summed into per-block
// double partials. Replaces old k_histr(lvl1) + k_sum.
// ---------------------------------------------------------------------------
__global__ __launch_bounds__(256) void k_hist3(
    const uint4* __restrict__ lb, const Ctrl* __restrict__ ctrl,
    unsigned* __restrict__ comb2, double* __restrict__ partials)
{
    __shared__ unsigned h[H2B];
    __shared__ double wsum[4];
    unsigned p2 = ctrl->p2;
    int t = threadIdx.x;
    #pragma unroll
    for (int j = t; j < H2B; j += 256) h[j] = 0;
    __syncthreads();
    int base = blockIdx.x * (NT4 / HB);
    double acc = 0.0;
    #pragma unroll
    for (int i = 0; i < NT4 / HB / 256; ++i) {
        uint4 v = lb[base + i * 256 + t];
        unsigned px = v.x >> 10, py = v.y >> 10, pz = v.z >> 10, pw = v.w >> 10;
        if (px == p2) atomicAdd(&h[v.x & 1023u], 1u);
        else if (px > p2) acc += (double)__uint_as_float(v.x);
        if (py == p2) atomicAdd(&h[v.y & 1023u], 1u);
        else if (py > p2) acc += (double)__uint_as_float(v.y);
        if (pz == p2) atomicAdd(&h[v.z & 1023u], 1u);
        else if (pz > p2) acc += (double)__uint_as_float(v.z);
        if (pw == p2) atomicAdd(&h[v.w & 1023u], 1u);
        else if (pw > p2) acc += (double)__uint_as_float(v.w);
    }
    __syncthreads();
    for (int j = t; j < H2B; j += 256)
        if (h[j]) atomicAdd(&comb2[j], h[j]);
    #pragma unroll
    for (int off = 32; off > 0; off >>= 1) acc += __shfl_down(acc, off, 64);
    int lane = t & 63, wid = t >> 6;
    if (lane == 0) wsum[wid] = acc;
    __syncthreads();
    if (t == 0) partials[blockIdx.x] = wsum[0] + wsum[1] + wsum[2] + wsum[3];
}

// ---------------------------------------------------------------------------
// S3+FINAL: suffix-scan comb2 -> exact threshold T and tie count r2; the top-k
// sum = sum(partials) + sum_{b>b3} count[b]*value(p2,b) + r2*T. One dispatch.
// ---------------------------------------------------------------------------
__global__ __launch_bounds__(256) void k_fin(
    const unsigned* __restrict__ comb2, const double* __restrict__ partials,
    const Ctrl* __restrict__ ctrl, float* __restrict__ out)
{
    __shared__ unsigned bins[H2B];
    __shared__ unsigned cs[256];
    __shared__ unsigned sh_t0, sh_base, sh_b3, sh_r2;
    __shared__ double wsum[4];
    int t = threadIdx.x;
    unsigned need = ctrl->n2, p2 = ctrl->p2;
    for (int j = t; j < H2B; j += 256) bins[j] = comb2[j];
    __syncthreads();
    unsigned sum = bins[t*4] + bins[t*4+1] + bins[t*4+2] + bins[t*4+3];
    cs[t] = sum; __syncthreads();
    for (int off = 1; off < 256; off <<= 1) {
        unsigned v = (t + off < 256) ? cs[t + off] : 0u;
        __syncthreads();
        cs[t] += v;
        __syncthreads();
    }
    unsigned St = cs[t], Sn = (t < 255) ? cs[t + 1] : 0u;
    if (St >= need && Sn < need) { sh_t0 = (unsigned)t; sh_base = Sn; }
    __syncthreads();
    if (t == 0) {
        unsigned cum = sh_base;
        for (int b = (int)sh_t0 * 4 + 3;; --b) {
            unsigned c = bins[b];
            if (cum + c >= need) { sh_b3 = (unsigned)b; sh_r2 = need - cum; break; }
            cum += c;
        }
    }
    __syncthreads();
    int b3 = (int)sh_b3;
    double acc = partials[t] + partials[t + 256];
    #pragma unroll
    for (int k = 0; k < 4; ++k) {
        int b = t * 4 + k;
        if (b > b3 && bins[b])
            acc += (double)bins[b] * (double)__uint_as_float((p2 << 10) | (unsigned)b);
    }
    #pragma unroll
    for (int off = 32; off > 0; off >>= 1) acc += __shfl_down(acc, off, 64);
    int lane = t & 63, wid = t >> 6;
    if (lane == 0) wsum[wid] = acc;
    __syncthreads();
    if (t == 0) {
        double tot = wsum[0] + wsum[1] + wsum[2] + wsum[3];
        unsigned Tb = (p2 << 10) | sh_b3;
        tot += (double)sh_r2 * (double)__uint_as_float(Tb);
        out[0] = (float)(tot / (double)KSEL);
    }
}

// ---------------------------------------------------------------------------
extern "C" void kernel_launch(void* const* d_in, const int* in_sizes, int n_in,
                              void* d_out, int out_size, void* d_ws, size_t ws_size,
                              hipStream_t stream)
{
    const float* logits = (const float*)d_in[0];
    // d_in[1] (labels, int64) is unused by the reference
    const float* smooth = (const float*)d_in[2];
    const float* wgt    = (const float*)d_in[3];

    char* ws = (char*)d_ws;
    float*    loss     = (float*)ws;
    unsigned* comb1    = (unsigned*)(ws + OFF_COMB1);
    unsigned* comb2    = (unsigned*)(ws + OFF_COMB2);
    double*   partials = (double*)(ws + OFF_PART);
    Ctrl*     ctrl     = (Ctrl*)(ws + OFF_CTRL);
    const uint4* lb    = (const uint4*)loss;

    k_loss <<<LBLK, 256, 0, stream>>>(logits, smooth, wgt, loss, comb1);
    k_hist1<<<HB,   256, 0, stream>>>(lb, comb1);
    k_sel1 <<<1,    256, 0, stream>>>(comb1, ctrl);
    k_hist2<<<HB,   256, 0, stream>>>(lb, ctrl, comb2);
    k_sel2 <<<1,    256, 0, stream>>>(comb2, ctrl);
    k_hist3<<<HB,   256, 0, stream>>>(lb, ctrl, comb2, partials);
    k_fin  <<<1,    256, 0, stream>>>(comb2, partials, ctrl, (float*)d_out);
}